// Round 13
// baseline (120.593 us; speedup 1.0000x reference)
//
#include <hip/hip_runtime.h>
#include <hip/hip_bf16.h>
#include <stdint.h>

typedef short s8v  __attribute__((ext_vector_type(8)));   // 8 bf16
typedef float f4v  __attribute__((ext_vector_type(4)));   // 16x16 MFMA C/D
typedef float f16v __attribute__((ext_vector_type(16)));  // 32x32 MFMA C/D

static __device__ __forceinline__ uint16_t f2bf(float f) {
    union { float f; uint32_t u; } v; v.f = f;
    uint32_t r = v.u + 0x7fffu + ((v.u >> 16) & 1u);
    return (uint16_t)(r >> 16);
}
static __device__ __forceinline__ uint32_t pk2(float lo, float hi) {
    return ((uint32_t)f2bf(hi) << 16) | (uint32_t)f2bf(lo);
}
// XOR-swizzled LDS offset (uint16 units) for [row][64] tiles, 128B rows.
static __device__ __forceinline__ int swz(int row, int col) {
    return row * 64 + (col ^ ((row & 7) * 8));
}
// async global->LDS, 16B per lane (dest = wave-uniform base + lane*16)
static __device__ __forceinline__ void gload_lds16(const void* g, void* l) {
    __builtin_amdgcn_global_load_lds(
        (const __attribute__((address_space(1))) uint32_t*)g,
        (__attribute__((address_space(3))) uint32_t*)l, 16, 0, 0);
}

// ---------------------------------------------------------------------------
// Kernel 0: weight transpose+convert.  w[3][512][64] fp32 -> wt[192][512] bf16
//   wt[p*64+h][k] = w[p][k][h] * (p==0 ? log2e/8 : 1)
// ---------------------------------------------------------------------------
__global__ __launch_bounds__(256) void wtrans(const float* __restrict__ w,
                                              uint16_t* __restrict__ wt) {
    __shared__ uint16_t lds[64][72];
    const int tid = threadIdx.x;
    const int p = blockIdx.x >> 3;
    const int kb = (blockIdx.x & 7) * 64;
    const float scale = (p == 0) ? 0.18033688011112042f : 1.0f;  // log2(e)/8

    #pragma unroll
    for (int i = 0; i < 16; ++i) {
        const int idx = i * 256 + tid;
        const int k = idx >> 6, h = idx & 63;
        lds[h][k] = f2bf(w[((size_t)(p * 512) + kb + k) * 64 + h] * scale);
    }
    __syncthreads();
    #pragma unroll
    for (int j = 0; j < 2; ++j) {
        const int c = j * 256 + tid;
        const int h = c >> 3, kc = (c & 7) * 8;
        *(s8v*)(wt + (size_t)(p * 64 + h) * 512 + kb + kc) = *(const s8v*)&lds[h][kc];
    }
}

// ---------------------------------------------------------------------------
// Kernel 0b: x fp32 -> bf16 one-pass convert (removes f2bf from GEMM loop).
// 4096 blocks x 256 threads; thread = 8 elements.
// ---------------------------------------------------------------------------
__global__ __launch_bounds__(256) void xconv(const float* __restrict__ x,
                                             uint16_t* __restrict__ xb) {
    const int i = (blockIdx.x * 256 + threadIdx.x) * 8;
    const float4 a = *(const float4*)(x + i);
    const float4 b = *(const float4*)(x + i + 4);
    s8v v;
    v[0] = (short)f2bf(a.x); v[1] = (short)f2bf(a.y);
    v[2] = (short)f2bf(a.z); v[3] = (short)f2bf(a.w);
    v[4] = (short)f2bf(b.x); v[5] = (short)f2bf(b.y);
    v[6] = (short)f2bf(b.z); v[7] = (short)f2bf(b.w);
    *(s8v*)(xb + i) = v;
}

// ---------------------------------------------------------------------------
// Kernel 1: QKV GEMM, m97-style.  xb[16384][512] bf16 @ wt[192][512] bf16.
// 256 blocks (128 rowblocks x 2 col-halves) x 256 threads (4 waves).
// BM=128, BN=96, BK=64; global_load_lds(16B) double-buffered staging;
// 2-phase loop: issue next-tile loads, ds_read + 24 MFMA, one barrier.
// ---------------------------------------------------------------------------
__global__ __launch_bounds__(256) void qkv_gemm(const uint16_t* __restrict__ xb,
                                                const uint16_t* __restrict__ wt,
                                                uint16_t* __restrict__ qo,
                                                uint16_t* __restrict__ ko,
                                                uint16_t* __restrict__ vto) {
    __shared__ __align__(16) uint16_t As[2][128 * 64];
    __shared__ __align__(16) uint16_t Bs[2][96 * 64];

    const int tid  = threadIdx.x;
    const int lane = tid & 63;
    const int wid  = tid >> 6;          // 0..3 -> 32-row slab
    const int row0 = (blockIdx.x >> 1) * 128;
    const int c0   = (blockIdx.x & 1) * 96;
    const int lr = lane & 15;
    const int lg = lane >> 4;
    const int gr = tid >> 3;            // 0..31: staging row within 32-row group
    const int gc = (tid & 7) * 8;       // staging col (bf16 units)

    f4v acc[2][6];
    #pragma unroll
    for (int i = 0; i < 2; ++i)
        #pragma unroll
        for (int j = 0; j < 6; ++j) acc[i][j] = (f4v){0.f, 0.f, 0.f, 0.f};

    // stage one BK=64 tile pair into buffer `bf` (linear LDS, lane-ordered)
    auto STAGE = [&](int bf, int kb) {
        #pragma unroll
        for (int i = 0; i < 4; ++i)       // A: 128x64 = 16 KB = 4 issues
            gload_lds16(xb + (size_t)(row0 + i * 32 + gr) * 512 + kb + gc,
                        &As[bf][i * 2048 + wid * 512]);
        #pragma unroll
        for (int i = 0; i < 3; ++i)       // B: 96x64 = 12 KB = 3 issues
            gload_lds16(wt + (size_t)(c0 + i * 32 + gr) * 512 + kb + gc,
                        &Bs[bf][i * 2048 + wid * 512]);
    };

    STAGE(0, 0);
    __syncthreads();

    int buf = 0;
    for (int t = 0; t < 8; ++t) {
        if (t < 7) STAGE(buf ^ 1, (t + 1) * 64);
        #pragma unroll
        for (int kk = 0; kk < 2; ++kk) {
            s8v a0 = *(const s8v*)&As[buf][(wid * 32 + lr) * 64 + kk * 32 + lg * 8];
            s8v a1 = *(const s8v*)&As[buf][(wid * 32 + 16 + lr) * 64 + kk * 32 + lg * 8];
            #pragma unroll
            for (int ct = 0; ct < 6; ++ct) {
                s8v b = *(const s8v*)&Bs[buf][(ct * 16 + lr) * 64 + kk * 32 + lg * 8];
                acc[0][ct] = __builtin_amdgcn_mfma_f32_16x16x32_bf16(a0, b, acc[0][ct], 0, 0, 0);
                acc[1][ct] = __builtin_amdgcn_mfma_f32_16x16x32_bf16(a1, b, acc[1][ct], 0, 0, 0);
            }
        }
        __syncthreads();   // drains vmcnt+lgkm: next buffer ready, this one free
        buf ^= 1;
    }

    // epilogue: D layout col = lane&15, row = (lane>>4)*4 + reg
    #pragma unroll
    for (int rt = 0; rt < 2; ++rt) {
        #pragma unroll
        for (int ct = 0; ct < 6; ++ct) {
            const int c = c0 + ct * 16 + lr;
            const int p = c >> 6, h = c & 63;
            #pragma unroll
            for (int r = 0; r < 4; ++r) {
                const int row = row0 + wid * 32 + rt * 16 + lg * 4 + r;
                const uint16_t val = f2bf(acc[rt][ct][r]);
                if (p == 0)      qo[(size_t)row * 64 + h] = val;
                else if (p == 1) ko[(size_t)row * 64 + h] = val;
                else {
                    const int bb = row >> 11, s = row & 2047;
                    vto[((size_t)bb * 64 + h) * 2048 + s] = val;
                }
            }
        }
    }
}

// ---------------------------------------------------------------------------
// Kernel 2: attention, swapped-QK 32x32 MFMA, lane-local no-max softmax.
// (unchanged from round 11 — controlled variable)
// ---------------------------------------------------------------------------
__global__ __launch_bounds__(256) void attn(const uint16_t* __restrict__ q,
                                            const uint16_t* __restrict__ k,
                                            const uint16_t* __restrict__ vt,
                                            float* __restrict__ opart,
                                            float* __restrict__ lpart,
                                            float* __restrict__ out,
                                            int nsplit) {
    __shared__ uint16_t kls[2][4096];   // [64 keys][64 dim], swizzled
    __shared__ uint16_t vls[2][4096];   // [64 h][64 keys],  swizzled

    const int tid = threadIdx.x;
    const int l   = tid & 63;
    const int wv  = tid >> 6;           // 0..3
    const int hi  = l >> 5;             // 0/1
    const int lo  = l & 31;
    const int sp   = blockIdx.x % nsplit;
    const int bq   = blockIdx.x / nsplit;
    const int b    = bq >> 4;
    const int qblk = bq & 15;           // 16 q-blocks of 128
    const int kspan = 2048 / nsplit;
    const int k0 = sp * kspan;
    const int ntiles = kspan / 64;
    const int qb0 = qblk * 128 + wv * 32;

    const uint16_t* qb = q  + (size_t)b * 2048 * 64;
    const uint16_t* kp = k  + (size_t)b * 2048 * 64;
    const uint16_t* vb = vt + (size_t)b * 64 * 2048;

    // Q fragments (B-operand): lane lo = q-row, dims d*16 + hi*8
    s8v qf[4];
    #pragma unroll
    for (int d = 0; d < 4; ++d)
        qf[d] = *(const s8v*)(qb + (size_t)(qb0 + lo) * 64 + d * 16 + hi * 8);

    f16v O0, O1;
    #pragma unroll
    for (int i = 0; i < 16; ++i) { O0[i] = 0.f; O1[i] = 0.f; }
    float lsum = 0.f;

    const int r1 = tid >> 3,         cc1 = (tid & 7) * 8;
    const int r2 = (tid + 256) >> 3, cc2 = (tid & 7) * 8;

    *(s8v*)&kls[0][swz(r1, cc1)] = *(const s8v*)(kp + (size_t)(k0 + r1) * 64 + cc1);
    *(s8v*)&kls[0][swz(r2, cc2)] = *(const s8v*)(kp + (size_t)(k0 + r2) * 64 + cc2);
    *(s8v*)&vls[0][swz(r1, cc1)] = *(const s8v*)(vb + (size_t)r1 * 2048 + k0 + cc1);
    *(s8v*)&vls[0][swz(r2, cc2)] = *(const s8v*)(vb + (size_t)r2 * 2048 + k0 + cc2);
    __syncthreads();

    int buf = 0;
    for (int t = 0; t < ntiles; ++t) {
        const int kb2 = k0 + t * 64;
        const bool more = (t + 1 < ntiles);
        s8v sk1, sk2, sv1, sv2;
        if (more) {
            sk1 = *(const s8v*)(kp + (size_t)(kb2 + 64 + r1) * 64 + cc1);
            sk2 = *(const s8v*)(kp + (size_t)(kb2 + 64 + r2) * 64 + cc2);
            sv1 = *(const s8v*)(vb + (size_t)r1 * 2048 + kb2 + 64 + cc1);
            sv2 = *(const s8v*)(vb + (size_t)r2 * 2048 + kb2 + 64 + cc2);
        }

        #pragma unroll
        for (int s = 0; s < 2; ++s) {      // two 32-key sub-tiles
            f16v sacc;
            #pragma unroll
            for (int i = 0; i < 16; ++i) sacc[i] = 0.f;
            #pragma unroll
            for (int d = 0; d < 4; ++d) {
                s8v kf = *(const s8v*)&kls[buf][swz(s * 32 + lo, d * 16 + hi * 8)];
                sacc = __builtin_amdgcn_mfma_f32_32x32x16_bf16(kf, qf[d], sacc, 0, 0, 0);
            }
            float p[16];
            #pragma unroll
            for (int r = 0; r < 16; ++r) p[r] = exp2f(sacc[r]);
            #pragma unroll
            for (int r = 0; r < 16; ++r) lsum += p[r];
            uint32_t w[8];
            #pragma unroll
            for (int j = 0; j < 8; ++j) w[j] = pk2(p[2 * j], p[2 * j + 1]);
            #pragma unroll
            for (int m = 0; m < 2; ++m) {
                const uint32_t s0 = hi ? w[4 * m + 0] : w[4 * m + 2];
                const uint32_t s1 = hi ? w[4 * m + 1] : w[4 * m + 3];
                const uint32_t r0 = (uint32_t)__shfl_xor((int)s0, 32, 64);
                const uint32_t rr = (uint32_t)__shfl_xor((int)s1, 32, 64);
                union { uint32_t u[4]; s8v v; } af;
                af.u[0] = hi ? r0 : w[4 * m + 0];
                af.u[1] = hi ? rr : w[4 * m + 1];
                af.u[2] = hi ? w[4 * m + 2] : r0;
                af.u[3] = hi ? w[4 * m + 3] : rr;
                const int g = s * 2 + m;
                s8v vf0 = *(const s8v*)&vls[buf][swz(lo,      g * 16 + hi * 8)];
                s8v vf1 = *(const s8v*)&vls[buf][swz(32 + lo, g * 16 + hi * 8)];
                O0 = __builtin_amdgcn_mfma_f32_32x32x16_bf16(af.v, vf0, O0, 0, 0, 0);
                O1 = __builtin_amdgcn_mfma_f32_32x32x16_bf16(af.v, vf1, O1, 0, 0, 0);
            }
        }

        if (more) {
            *(s8v*)&kls[buf ^ 1][swz(r1, cc1)] = sk1;
            *(s8v*)&kls[buf ^ 1][swz(r2, cc2)] = sk2;
            *(s8v*)&vls[buf ^ 1][swz(r1, cc1)] = sv1;
            *(s8v*)&vls[buf ^ 1][swz(r2, cc2)] = sv2;
        }
        __syncthreads();
        buf ^= 1;
    }

    lsum += __shfl_xor(lsum, 32, 64);

    if (nsplit == 1) {
        const float inv = 1.0f / lsum;
        #pragma unroll
        for (int r = 0; r < 16; ++r) {
            const int qrow = (r & 3) + 8 * (r >> 2) + 4 * hi;
            const size_t grow = (size_t)b * 2048 + qb0 + qrow;
            out[grow * 64 + lo]      = O0[r] * inv;
            out[grow * 64 + 32 + lo] = O1[r] * inv;
        }
    } else {
        #pragma unroll
        for (int r = 0; r < 16; ++r) {
            const int qrow = (r & 3) + 8 * (r >> 2) + 4 * hi;
            const size_t grow = (size_t)sp * 16384 + (size_t)b * 2048 + qb0 + qrow;
            opart[grow * 64 + lo]      = O0[r];
            opart[grow * 64 + 32 + lo] = O1[r];
        }
        if (l < 32)
            lpart[(size_t)sp * 16384 + (size_t)b * 2048 + qb0 + l] = lsum;
    }
}

// ---------------------------------------------------------------------------
// Kernel 3: combine 4 K-split partials (plain sums, no exp weights).
// ---------------------------------------------------------------------------
__global__ __launch_bounds__(256) void combine(const float* __restrict__ opart,
                                               const float* __restrict__ lpart,
                                               float* __restrict__ out) {
    const int idx = blockIdx.x * 256 + threadIdx.x;   // 262144 = 16384*16
    const int row = idx >> 4;
    const int hq = (idx & 15) * 4;

    const float inv = 1.0f / (lpart[row] + lpart[16384 + row] +
                              lpart[2 * 16384 + row] + lpart[3 * 16384 + row]);

    const float4 o0 = *(const float4*)(opart + ((size_t)0 * 16384 + row) * 64 + hq);
    const float4 o1 = *(const float4*)(opart + ((size_t)1 * 16384 + row) * 64 + hq);
    const float4 o2 = *(const float4*)(opart + ((size_t)2 * 16384 + row) * 64 + hq);
    const float4 o3 = *(const float4*)(opart + ((size_t)3 * 16384 + row) * 64 + hq);

    float4 res;
    res.x = (o0.x + o1.x + o2.x + o3.x) * inv;
    res.y = (o0.y + o1.y + o2.y + o3.y) * inv;
    res.z = (o0.z + o1.z + o2.z + o3.z) * inv;
    res.w = (o0.w + o1.w + o2.w + o3.w) * inv;
    *(float4*)(out + (size_t)row * 64 + hq) = res;
}

extern "C" void kernel_launch(void* const* d_in, const int* in_sizes, int n_in,
                              void* d_out, int out_size, void* d_ws, size_t ws_size,
                              hipStream_t stream) {
    const float* x = (const float*)d_in[0];
    const float* w = (const float*)d_in[1];
    char* ws = (char*)d_ws;
    uint16_t* qw = (uint16_t*)(ws);                  // 2 MB
    uint16_t* kw = (uint16_t*)(ws + 2097152);        // 2 MB
    uint16_t* vw = (uint16_t*)(ws + 4194304);        // 2 MB  (V^T [b][h][s])
    uint16_t* wt = (uint16_t*)(ws + 6291456);        // 192 KB (w^T bf16, scaled)
    uint16_t* xb = (uint16_t*)(ws + 6488064);        // 16 MB (x as bf16)
    float*  opart = (float*)(ws + 23265280);         // 16 MB (4 splits)
    float*  lpart = (float*)(ws + 40042496);         // 256 KB
    float* out = (float*)d_out;

    const int nsplit = (ws_size >= 40304640) ? 4 : 1;

    wtrans<<<24, 256, 0, stream>>>(w, wt);
    xconv<<<4096, 256, 0, stream>>>(x, xb);
    qkv_gemm<<<256, 256, 0, stream>>>(xb, wt, qw, kw, vw);
    attn<<<128 * nsplit, 256, 0, stream>>>(qw, kw, vw, opart, lpart, out, nsplit);
    if (nsplit > 1) combine<<<1024, 256, 0, stream>>>(opart, lpart, out);
}